// Round 3
// baseline (124.688 us; speedup 1.0000x reference)
//
#include <hip/hip_runtime.h>

#define NB 8
#define NT 512
#define NS 512
#define NH 128
#define C2LOG2E 2.8853900817779268f   // 2*log2(e): exp2(C*x) = e^(2x)

__device__ __forceinline__ float fast_exp2(float x) { return __builtin_amdgcn_exp2f(x); }
__device__ __forceinline__ float fast_rcp(float x)  { return __builtin_amdgcn_rcpf(x); }
__device__ __forceinline__ float fast_tanh(float x) {
  float e = fast_exp2(x * C2LOG2E);
  return 1.0f - 2.0f * fast_rcp(e + 1.0f);
}

__device__ __forceinline__ float dot4(float4 a, float4 b) {
  return (a.x * b.x + a.y * b.y) + (a.z * b.z + a.w * b.w);
}

// acc.c += sum_{i=0..3} v_i/(e_i*F_i.c+1): 4-term rational combine,
// ONE rcp per component. den = product of four (1+e^{2x}) terms: worst-case
// ~e^64, no fp32 overflow.
__device__ __forceinline__ float2 quad_acc2(float4 e, float4 vv,
                                            float2 F0, float2 F1,
                                            float2 F2, float2 F3, float2 acc) {
  float P0x = fmaf(e.x, F0.x, 1.f), P0y = fmaf(e.x, F0.y, 1.f);
  float P1x = fmaf(e.y, F1.x, 1.f), P1y = fmaf(e.y, F1.y, 1.f);
  float P2x = fmaf(e.z, F2.x, 1.f), P2y = fmaf(e.z, F2.y, 1.f);
  float P3x = fmaf(e.w, F3.x, 1.f), P3y = fmaf(e.w, F3.y, 1.f);
  float d01x = P0x * P1x, d01y = P0y * P1y;
  float d23x = P2x * P3x, d23y = P2y * P3y;
  float n01x = fmaf(vv.x, P1x, vv.y * P0x);
  float n01y = fmaf(vv.x, P1y, vv.y * P0y);
  float n23x = fmaf(vv.z, P3x, vv.w * P2x);
  float n23y = fmaf(vv.z, P3y, vv.w * P2y);
  float numx = fmaf(n01x, d23x, n23x * d01x);
  float numy = fmaf(n01y, d23y, n23y * d01y);
  acc.x = fmaf(numx, fast_rcp(d01x * d23x), acc.x);
  acc.y = fmaf(numy, fast_rcp(d01y * d23y), acc.y);
  return acc;
}

// ---------------- K1: four 4096x128x128 GEMMs ----------------
// set 0: EWS  = exp2(C*(q  @ W_s^T))            [b][t][h]
// set 1: EWHT = exp2(C*(enc@ W_h^T)) TRANSPOSED [b][h][s]
// set 2: ENCW = enc @ W1^T   (W1 = Wout[:, :128])        [b][s][c]
// set 3: QW2  = q @ W2^T + b (W2 = Wout[:, 128:])        [b][t][c]
// Producer XCD matching for the mega kernel's sliding-window consumer map:
//  - t-partitioned outputs (EWS, QW2): chunk (b, rc) produced on XCD
//    (b - rc/4) & 7 == the XCD whose mega blocks read those t-rows.
//  - s-partitioned outputs (EWHT, ENCW): read by 4 XCDs; keep on XCD b
//    (1-of-4 consumers local, rest served by L2-of-b / L3).
__global__ __launch_bounds__(256) void bah_proj_kernel(
    const float* __restrict__ query, const float* __restrict__ enc,
    const float* __restrict__ W_s, const float* __restrict__ W_h,
    const float* __restrict__ Wout, const float* __restrict__ Woutb,
    float* __restrict__ EWS, float* __restrict__ EWHT,
    float* __restrict__ ENCW, float* __restrict__ QW2) {
  __shared__ __align__(16) float lds_w[64 * 132];   // 33.8 KB: one col-half
  __shared__ __align__(16) float lds_x[32 * 132];   // 16.9 KB; reused 64x33
  const int set = blockIdx.x >> 8;
  const int u   = blockIdx.x & 255;
  const int x   = u & 7;            // == XCD id (round-robin dispatch, %8)
  const int g   = u >> 3;           // 32 blocks per XCD per set
  int b, rc, ch;
  if (set == 0 || set == 3) {       // t-partitioned: match mega window slot
    int d = g >> 3;                 // slot = rc>>2
    rc = (d << 2) | ((g >> 1) & 3);
    ch = g & 1;
    b  = (x + d) & 7;
  } else {                          // s-partitioned: keep batch on XCD b
    rc = g >> 1;
    ch = g & 1;
    b  = x;
  }
  const int r0 = ((b << 4) | rc) * 32;   // row block in [0,4096)
  const int c0 = ch * 64;
  const int tid = threadIdx.x;
  const float* in = (set == 1 || set == 2) ? enc : query;
  const float* Wb; int wst;
  if (set == 0)      { Wb = W_s;        wst = 128; }
  else if (set == 1) { Wb = W_h;        wst = 128; }
  else if (set == 2) { Wb = Wout;       wst = 256; }
  else               { Wb = Wout + 128; wst = 256; }
  for (int i = tid; i < 2048; i += 256) {           // W: 64 rows x 32 float4
    int r = i >> 5, c4 = i & 31;
    *(float4*)(lds_w + r * 132 + c4 * 4) =
        *(const float4*)(Wb + (c0 + r) * wst + c4 * 4);
  }
  for (int i = tid; i < 1024; i += 256) {           // x: 32 rows x 32 float4
    int r = i >> 5, c4 = i & 31;
    *(float4*)(lds_x + r * 132 + c4 * 4) =
        *(const float4*)(in + (r0 + r) * NH + c4 * 4);
  }
  __syncthreads();
  const int cg = tid & 31;         // cols c0+cg, c0+cg+32
  const int rg = tid >> 5;         // rows rg*4 .. rg*4+3
  float acc[4][2] = {{0,0},{0,0},{0,0},{0,0}};
  for (int k4 = 0; k4 < 32; ++k4) {
    float4 xa[4], wb[2];
    #pragma unroll
    for (int i = 0; i < 4; ++i)      // wave-uniform addr -> broadcast
      xa[i] = *(const float4*)(lds_x + (rg * 4 + i) * 132 + k4 * 4);
    #pragma unroll
    for (int m = 0; m < 2; ++m)      // bank = (cg+k4)%32 -> conflict-free
      wb[m] = *(const float4*)(lds_w + (cg + 32 * m) * 132 + k4 * 4);
    #pragma unroll
    for (int i = 0; i < 4; ++i)
      #pragma unroll
      for (int m = 0; m < 2; ++m)
        acc[i][m] += dot4(xa[i], wb[m]);
  }
  if (set == 0) {
    #pragma unroll
    for (int i = 0; i < 4; ++i)
      #pragma unroll
      for (int m = 0; m < 2; ++m)    // lanes cg consecutive -> coalesced
        EWS[(r0 + rg * 4 + i) * NH + c0 + cg + 32 * m] =
            fast_exp2(C2LOG2E * acc[i][m]);
  } else if (set == 1) {
    __syncthreads();                 // lds_x dead; reuse as 64x33 transpose
    #pragma unroll
    for (int i = 0; i < 4; ++i)
      #pragma unroll
      for (int m = 0; m < 2; ++m)
        lds_x[(cg + 32 * m) * 33 + rg * 4 + i] = fast_exp2(C2LOG2E * acc[i][m]);
    __syncthreads();
    const int sl0 = r0 & 511;
    const int s_lane = tid & 31, hr = tid >> 5;   // 8 groups x 8 h-rows
    #pragma unroll
    for (int j = 0; j < 8; ++j)      // lanes s consecutive -> coalesced 128B
      EWHT[b * NH * NS + (c0 + hr * 8 + j) * NS + sl0 + s_lane] =
          lds_x[(hr * 8 + j) * 33 + s_lane];
  } else if (set == 2) {
    #pragma unroll
    for (int i = 0; i < 4; ++i)
      #pragma unroll
      for (int m = 0; m < 2; ++m)
        ENCW[(r0 + rg * 4 + i) * NH + c0 + cg + 32 * m] = acc[i][m];
  } else {
    #pragma unroll
    for (int i = 0; i < 4; ++i)
      #pragma unroll
      for (int m = 0; m < 2; ++m) {
        int c = c0 + cg + 32 * m;    // bias folded here, not in mega
        QW2[(r0 + rg * 4 + i) * NH + c] = acc[i][m] + Woutb[c];
      }
  }
}

// -------- K2: MEGA — scores + quirky softmax + attn x ENCW -> out ---------
// 512 threads, grid 512. Sliding-window map: XCD x serves batches
// {x, x+1, x+2, x+3} (16 t-chunks each). Working set/XCD ~2.5MB < 4MB L2
// (locality kept) AND per-XCD work = 4-batch window average (balance fixed:
// r2's bb=blk&7 put all of forced-len-512 batch 0 on XCD 0 -> runtime = max
// XCD = full-length batch; occupancy fell to 18%).
__global__ __launch_bounds__(512) void bah_mega_kernel(
    const float* __restrict__ EWS, const float* __restrict__ EWHT,
    const float* __restrict__ v, const float* __restrict__ ENCW,
    const float* __restrict__ QW2, const int* __restrict__ src_len,
    float* __restrict__ out) {
  // Arena (floats): s_v[0,128) s_et[128,1184) s_aT[1184,5280)
  // s_par[5280,9632) s_sc[9632,13760) s_red[13760,13824).
  // lred (phase D) overlays s_par+s_sc (needs 8192 <= 8480).
  __shared__ __align__(16) float smem[13824];
  float* s_v   = smem;
  float* s_et  = smem + 128;
  float* s_aT  = smem + 1184;
  float* s_par = smem + 5280;
  float* s_sc  = smem + 9632;
  float* s_red = smem + 13760;

  const int tid = threadIdx.x;
  const int x  = blockIdx.x & 7;          // XCD id
  const int j  = blockIdx.x >> 3;         // 64 blocks per XCD
  const int sl = j & 3;                   // window slot
  const int bb = (x + sl) & 7;            // batch
  const int t0 = (sl * 16 + (j >> 2)) * 8;
  const int len = src_len[bb];

  if (tid < 32) *(float4*)(s_v + tid * 4) = *(const float4*)(v + tid * 4);
  if (tid < 256) {                     // 8x128 EWS rows = 256 float4
    int r = tid >> 5, c4 = tid & 31;
    *(float4*)(s_et + r * 132 + c4 * 4) =
        *(const float4*)(EWS + (bb * NT + t0 + r) * NH + c4 * 4);
  }
  __syncthreads();

  // V0 = sum(v) via one float2 read + wave shuffles (all lanes get it)
  float V0;
  {
    float2 vv = *(const float2*)(s_v + (tid & 63) * 2);
    V0 = vv.x + vv.y;
    #pragma unroll
    for (int msk = 1; msk <= 32; msk <<= 1)
      V0 += __shfl_xor(V0, msk, 64);
  }

  // ---- Phase B: scores. tg=tid>>8 (h-half), sp=tid&255 (2 contiguous s),
  // each thread owns all 8 t-rows. Wave-level skip of fully-masked s-spans.
  // ho-loop software-pipelined: next iteration's 8 EWHT loads issue before
  // the current iteration's compute.
  const int tg = tid >> 8, sp = tid & 255;
  const int sbase = sp * 2;
  const int h0 = tg * 64;
  float2 acc2[8];
  #pragma unroll
  for (int i = 0; i < 8; ++i) { acc2[i].x = 0.f; acc2[i].y = 0.f; }
  const int wave_s0 = (sp & ~63) * 2;     // wave-uniform start of 128-s span
  if (wave_s0 < len) {
    const float* fb = EWHT + bb * NH * NS + h0 * NS + sbase;
    float2 F[8];
    #pragma unroll
    for (int jj = 0; jj < 8; ++jj) F[jj] = *(const float2*)(fb + jj * NS);
    for (int ho = 0; ho < 8; ++ho) {
      float2 Fn[8];
      if (ho < 7) {
        const float* fh = fb + (ho + 1) * 8 * NS;
        #pragma unroll
        for (int jj = 0; jj < 8; ++jj) Fn[jj] = *(const float2*)(fh + jj * NS);
      }
      float4 va = *(const float4*)(s_v + h0 + ho * 8);
      float4 vb = *(const float4*)(s_v + h0 + ho * 8 + 4);
      #pragma unroll
      for (int tt = 0; tt < 8; ++tt) {
        float4 e0 = *(const float4*)(s_et + tt * 132 + h0 + ho * 8);  // bcast
        float4 e1 = *(const float4*)(s_et + tt * 132 + h0 + ho * 8 + 4);
        acc2[tt] = quad_acc2(e0, va, F[0], F[1], F[2], F[3], acc2[tt]);
        acc2[tt] = quad_acc2(e1, vb, F[4], F[5], F[6], F[7], acc2[tt]);
      }
      #pragma unroll
      for (int jj = 0; jj < 8; ++jj) F[jj] = Fn[jj];
    }
  }
  if (tg == 1) {                       // stride 17: gcd(17,32)=1, conflict-free
    #pragma unroll
    for (int tt = 0; tt < 8; ++tt)
      *(float2*)(s_par + sp * 17 + tt * 2) = acc2[tt];
  }
  __syncthreads();
  if (tg == 0) {
    #pragma unroll
    for (int tt = 0; tt < 8; ++tt) {
      float2 oth = *(const float2*)(s_par + sp * 17 + tt * 2);
      float sx = acc2[tt].x + oth.x;
      float sy = acc2[tt].y + oth.y;
      float2 r;  // faithful quirk: masked scores ZEROED, still in softmax
      r.x = (sbase + 0 < len) ? fmaf(-2.f, sx, V0) : 0.f;
      r.y = (sbase + 1 < len) ? fmaf(-2.f, sy, V0) : 0.f;
      *(float2*)(s_sc + tt * 516 + sbase) = r;
    }
  }
  __syncthreads();

  // ---- Phase C: softmax per t-row; attn transposed into s_aT ----
  const int t = tid & 7;
  const int c = tid >> 3;       // 0..63, 8 strided s values each
  const int wv = tid >> 6;
  float pv[8];
  float mx = -3.4e38f;
  #pragma unroll
  for (int k = 0; k < 8; ++k) {
    pv[k] = s_sc[t * 516 + c + 64 * k];
    mx = fmaxf(mx, pv[k]);
  }
  #pragma unroll
  for (int msk = 8; msk <= 32; msk <<= 1)
    mx = fmaxf(mx, __shfl_xor(mx, msk, 64));
  if ((tid & 63) < 8) s_red[wv * 8 + t] = mx;
  __syncthreads();
  #pragma unroll
  for (int jj = 1; jj < 8; ++jj) mx = fmaxf(mx, s_red[jj * 8 + t]);
  mx = fmaxf(mx, s_red[t]);
  __syncthreads();              // all reads done before red is rewritten
  float sum = 0.f;
  #pragma unroll
  for (int k = 0; k < 8; ++k) {
    pv[k] = fast_exp2((pv[k] - mx) * 1.4426950408889634f);
    sum += pv[k];
  }
  #pragma unroll
  for (int msk = 8; msk <= 32; msk <<= 1)
    sum += __shfl_xor(sum, msk, 64);
  if ((tid & 63) < 8) s_red[wv * 8 + t] = sum;
  __syncthreads();
  sum = 0.f;
  #pragma unroll
  for (int jj = 0; jj < 8; ++jj) sum += s_red[jj * 8 + t];
  const float rd = fast_rcp(sum);
  #pragma unroll
  for (int k = 0; k < 8; ++k)   // word 8(c+64k)+t: consecutive per wave
    s_aT[(c + 64 * k) * 8 + t] = pv[k] * rd;
  __syncthreads();

  // ---- Phase D': pre_out[t][c] = sum_s attn[t][s] * ENCW[s][c] ----
  // Branchless (masked s already carry the correct uniform weight in s_aT);
  // k-loop software-pipelined: next ENCW row prefetched before compute.
  const int hg = tid & 31, sg = tid >> 5;   // 16 s-groups x 32 s
  float4 a8[8] = {{0,0,0,0},{0,0,0,0},{0,0,0,0},{0,0,0,0},
                  {0,0,0,0},{0,0,0,0},{0,0,0,0},{0,0,0,0}};
  const float* eb = ENCW + bb * NS * NH + hg * 4;
  float4 e = *(const float4*)(eb + (sg * 32) * NH);
  for (int k = 0; k < 32; ++k) {
    int s = sg * 32 + k;
    float4 en = e;
    if (k < 31) en = *(const float4*)(eb + (s + 1) * NH);  // prefetch
    float4 w0 = *(const float4*)(s_aT + s * 8);     // 2 addrs/wave: free
    float4 w1 = *(const float4*)(s_aT + s * 8 + 4);
    a8[0].x += w0.x*e.x; a8[0].y += w0.x*e.y; a8[0].z += w0.x*e.z; a8[0].w += w0.x*e.w;
    a8[1].x += w0.y*e.x; a8[1].y += w0.y*e.y; a8[1].z += w0.y*e.z; a8[1].w += w0.y*e.w;
    a8[2].x += w0.z*e.x; a8[2].y += w0.z*e.y; a8[2].z += w0.z*e.z; a8[2].w += w0.z*e.w;
    a8[3].x += w0.w*e.x; a8[3].y += w0.w*e.y; a8[3].z += w0.w*e.z; a8[3].w += w0.w*e.w;
    a8[4].x += w1.x*e.x; a8[4].y += w1.x*e.y; a8[4].z += w1.x*e.z; a8[4].w += w1.x*e.w;
    a8[5].x += w1.y*e.x; a8[5].y += w1.y*e.y; a8[5].z += w1.y*e.z; a8[5].w += w1.y*e.w;
    a8[6].x += w1.z*e.x; a8[6].y += w1.z*e.y; a8[6].z += w1.z*e.z; a8[6].w += w1.z*e.w;
    a8[7].x += w1.w*e.x; a8[7].y += w1.w*e.y; a8[7].z += w1.w*e.z; a8[7].w += w1.w*e.w;
    e = en;
  }
  #pragma unroll
  for (int i = 0; i < 8; ++i) {     // sg pairs within wave (lane^32)
    a8[i].x += __shfl_xor(a8[i].x, 32, 64);
    a8[i].y += __shfl_xor(a8[i].y, 32, 64);
    a8[i].z += __shfl_xor(a8[i].z, 32, 64);
    a8[i].w += __shfl_xor(a8[i].w, 32, 64);
  }
  float* lred = s_par;              // overlays par+sc (both dead): 8192 fl
  if ((tid & 63) < 32) {
    #pragma unroll
    for (int i = 0; i < 8; ++i)
      *(float4*)(lred + wv * 1024 + i * 128 + hg * 4) = a8[i];
  }
  __syncthreads();
  if (tid < 256) {                  // final reduce + QW2 (has bias) + tanh
    int tt = tid >> 5, hh = tid & 31;
    float4 o = {0.f, 0.f, 0.f, 0.f};
    #pragma unroll
    for (int jj = 0; jj < 8; ++jj) {
      float4 p = *(const float4*)(lred + jj * 1024 + tt * 128 + hh * 4);
      o.x += p.x; o.y += p.y; o.z += p.z; o.w += p.w;
    }
    const int row = bb * NT + t0 + tt;
    float4 q4 = *(const float4*)(QW2 + row * NH + hh * 4);  // coalesced
    float4 r;
    r.x = fast_tanh(o.x + q4.x);
    r.y = fast_tanh(o.y + q4.y);
    r.z = fast_tanh(o.z + q4.z);
    r.w = fast_tanh(o.w + q4.w);
    *(float4*)(out + row * NH + hh * 4) = r;
  }
}

extern "C" void kernel_launch(void* const* d_in, const int* in_sizes, int n_in,
                              void* d_out, int out_size, void* d_ws, size_t ws_size,
                              hipStream_t stream) {
  const float* query = (const float*)d_in[0];
  const float* enc   = (const float*)d_in[1];
  const int*   slen  = (const int*)d_in[2];
  const float* W_h   = (const float*)d_in[3];
  const float* W_s   = (const float*)d_in[4];
  const float* v     = (const float*)d_in[5];
  const float* Woutw = (const float*)d_in[6];
  const float* Woutb = (const float*)d_in[7];
  float* out = (float*)d_out;

  float* ws = (float*)d_ws;
  float* EWS  = ws;                  // B*T*H (2 MB)
  float* EWHT = ws + 524288;         // B*H*S transposed (2 MB)
  float* ENCW = ws + 1048576;        // B*S*H = enc @ W1^T (2 MB)
  float* QW2  = ws + 1572864;        // B*T*H = q @ W2^T + bias (2 MB)

  bah_proj_kernel<<<1024, 256, 0, stream>>>(query, enc, W_s, W_h, Woutw,
                                            Woutb, EWS, EWHT, ENCW, QW2);
  bah_mega_kernel<<<512, 512, 0, stream>>>(EWS, EWHT, v, ENCW, QW2, slen, out);
}

// Round 4
// 117.951 us; speedup vs baseline: 1.0571x; 1.0571x over previous
//
#include <hip/hip_runtime.h>

#define NB 8
#define NT 512
#define NS 512
#define NH 128
#define C2LOG2E 2.8853900817779268f   // 2*log2(e): exp2(C*x) = e^(2x)

__device__ __forceinline__ float fast_exp2(float x) { return __builtin_amdgcn_exp2f(x); }
__device__ __forceinline__ float fast_rcp(float x)  { return __builtin_amdgcn_rcpf(x); }
__device__ __forceinline__ float fast_tanh(float x) {
  float e = fast_exp2(x * C2LOG2E);
  return 1.0f - 2.0f * fast_rcp(e + 1.0f);
}

__device__ __forceinline__ float dot4(float4 a, float4 b) {
  return (a.x * b.x + a.y * b.y) + (a.z * b.z + a.w * b.w);
}

// acc.c += sum_{i=0..3} v_i/(e_i*F_i.c+1): 4-term rational combine,
// ONE rcp per component. den = product of four (1+e^{2x}) terms: worst-case
// ~e^64, no fp32 overflow.
__device__ __forceinline__ float2 quad_acc2(float4 e, float4 vv,
                                            float2 F0, float2 F1,
                                            float2 F2, float2 F3, float2 acc) {
  float P0x = fmaf(e.x, F0.x, 1.f), P0y = fmaf(e.x, F0.y, 1.f);
  float P1x = fmaf(e.y, F1.x, 1.f), P1y = fmaf(e.y, F1.y, 1.f);
  float P2x = fmaf(e.z, F2.x, 1.f), P2y = fmaf(e.z, F2.y, 1.f);
  float P3x = fmaf(e.w, F3.x, 1.f), P3y = fmaf(e.w, F3.y, 1.f);
  float d01x = P0x * P1x, d01y = P0y * P1y;
  float d23x = P2x * P3x, d23y = P2y * P3y;
  float n01x = fmaf(vv.x, P1x, vv.y * P0x);
  float n01y = fmaf(vv.x, P1y, vv.y * P0y);
  float n23x = fmaf(vv.z, P3x, vv.w * P2x);
  float n23y = fmaf(vv.z, P3y, vv.w * P2y);
  float numx = fmaf(n01x, d23x, n23x * d01x);
  float numy = fmaf(n01y, d23y, n23y * d01y);
  acc.x = fmaf(numx, fast_rcp(d01x * d23x), acc.x);
  acc.y = fmaf(numy, fast_rcp(d01y * d23y), acc.y);
  return acc;
}

// ---------------- K1: four 4096x128x128 GEMMs ----------------
// set 0: EWS  = exp2(C*(q  @ W_s^T))            [b][t][h]
// set 1: EWHT = exp2(C*(enc@ W_h^T)) TRANSPOSED [b][h][s]
// set 2: ENCW = enc @ W1^T   (W1 = Wout[:, :128])        [b][s][c]
// set 3: QW2  = q @ W2^T + b (W2 = Wout[:, 128:])        [b][t][c]
// (r0 decode restored: XCD producer-matching gave no measurable gain.)
__global__ __launch_bounds__(256) void bah_proj_kernel(
    const float* __restrict__ query, const float* __restrict__ enc,
    const float* __restrict__ W_s, const float* __restrict__ W_h,
    const float* __restrict__ Wout, const float* __restrict__ Woutb,
    float* __restrict__ EWS, float* __restrict__ EWHT,
    float* __restrict__ ENCW, float* __restrict__ QW2) {
  __shared__ __align__(16) float lds_w[64 * 132];   // 33.8 KB: one col-half
  __shared__ __align__(16) float lds_x[32 * 132];   // 16.9 KB; reused 64x33
  const int set = blockIdx.x >> 8;
  const int blk = blockIdx.x & 255;
  const int rb = blk >> 1, ch = blk & 1;
  const int r0 = rb * 32, c0 = ch * 64;
  const int tid = threadIdx.x;
  const float* in = (set == 1 || set == 2) ? enc : query;
  const float* Wb; int wst;
  if (set == 0)      { Wb = W_s;        wst = 128; }
  else if (set == 1) { Wb = W_h;        wst = 128; }
  else if (set == 2) { Wb = Wout;       wst = 256; }
  else               { Wb = Wout + 128; wst = 256; }
  for (int i = tid; i < 2048; i += 256) {           // W: 64 rows x 32 float4
    int r = i >> 5, c4 = i & 31;
    *(float4*)(lds_w + r * 132 + c4 * 4) =
        *(const float4*)(Wb + (c0 + r) * wst + c4 * 4);
  }
  for (int i = tid; i < 1024; i += 256) {           // x: 32 rows x 32 float4
    int r = i >> 5, c4 = i & 31;
    *(float4*)(lds_x + r * 132 + c4 * 4) =
        *(const float4*)(in + (r0 + r) * NH + c4 * 4);
  }
  __syncthreads();
  const int cg = tid & 31;         // cols c0+cg, c0+cg+32
  const int rg = tid >> 5;         // rows rg*4 .. rg*4+3
  float acc[4][2] = {{0,0},{0,0},{0,0},{0,0}};
  for (int k4 = 0; k4 < 32; ++k4) {
    float4 xa[4], wb[2];
    #pragma unroll
    for (int i = 0; i < 4; ++i)      // wave-uniform addr -> broadcast
      xa[i] = *(const float4*)(lds_x + (rg * 4 + i) * 132 + k4 * 4);
    #pragma unroll
    for (int m = 0; m < 2; ++m)      // bank = (cg+k4)%32 -> conflict-free
      wb[m] = *(const float4*)(lds_w + (cg + 32 * m) * 132 + k4 * 4);
    #pragma unroll
    for (int i = 0; i < 4; ++i)
      #pragma unroll
      for (int m = 0; m < 2; ++m)
        acc[i][m] += dot4(xa[i], wb[m]);
  }
  if (set == 0) {
    #pragma unroll
    for (int i = 0; i < 4; ++i)
      #pragma unroll
      for (int m = 0; m < 2; ++m)    // lanes cg consecutive -> coalesced
        EWS[(r0 + rg * 4 + i) * NH + c0 + cg + 32 * m] =
            fast_exp2(C2LOG2E * acc[i][m]);
  } else if (set == 1) {
    __syncthreads();                 // lds_x dead; reuse as 64x33 transpose
    #pragma unroll
    for (int i = 0; i < 4; ++i)
      #pragma unroll
      for (int m = 0; m < 2; ++m)
        lds_x[(cg + 32 * m) * 33 + rg * 4 + i] = fast_exp2(C2LOG2E * acc[i][m]);
    __syncthreads();
    const int b = r0 >> 9, sl0 = r0 & 511;
    const int s_lane = tid & 31, hr = tid >> 5;   // 8 groups x 8 h-rows
    #pragma unroll
    for (int j = 0; j < 8; ++j)      // lanes s consecutive -> coalesced 128B
      EWHT[b * NH * NS + (c0 + hr * 8 + j) * NS + sl0 + s_lane] =
          lds_x[(hr * 8 + j) * 33 + s_lane];
  } else if (set == 2) {
    #pragma unroll
    for (int i = 0; i < 4; ++i)
      #pragma unroll
      for (int m = 0; m < 2; ++m)
        ENCW[(r0 + rg * 4 + i) * NH + c0 + cg + 32 * m] = acc[i][m];
  } else {
    #pragma unroll
    for (int i = 0; i < 4; ++i)
      #pragma unroll
      for (int m = 0; m < 2; ++m) {
        int c = c0 + cg + 32 * m;    // bias folded here, not in mega
        QW2[(r0 + rg * 4 + i) * NH + c] = acc[i][m] + Woutb[c];
      }
  }
}

// -------- K2: MEGA — scores + quirky softmax + attn x ENCW -> out ---------
// RESTRUCTURED for latency: 256 threads, 4 t-rows/block, grid 1024.
// LDS 19.2 KB (was 55) -> up to 8 blocks/CU; 4 resident from grid. Each
// thread owns ALL 128 h for its 2 s-columns -> no cross-h partial-sum
// buffer (s_par gone, one fewer barrier); barriers rendezvous 4 waves
// not 8; 4 independent blocks/CU interleave phases to hide latency.
__global__ __launch_bounds__(256) void bah_mega_kernel(
    const float* __restrict__ EWS, const float* __restrict__ EWHT,
    const float* __restrict__ v, const float* __restrict__ ENCW,
    const float* __restrict__ QW2, const int* __restrict__ src_len,
    float* __restrict__ out) {
  // Arena (floats): s_v[0,128) s_et[128,656) s_aT[656,2704)
  // s_sc[2704,4768) s_red[4768,4784). lred (phase D, 2048) overlays s_sc.
  __shared__ __align__(16) float smem[4784];
  float* s_v   = smem;
  float* s_et  = smem + 128;
  float* s_aT  = smem + 656;
  float* s_sc  = smem + 2704;
  float* s_red = smem + 4768;

  const int tid = threadIdx.x;
  const int bb = blockIdx.x >> 7;         // batch-major; %8 dispatch balances
  const int t0 = (blockIdx.x & 127) * 4;  // 4 t-rows per block
  const int len = src_len[bb];

  if (tid < 32) *(float4*)(s_v + tid * 4) = *(const float4*)(v + tid * 4);
  if (tid < 128) {                     // 4x128 EWS rows = 128 float4
    int r = tid >> 5, c4 = tid & 31;
    *(float4*)(s_et + r * 132 + c4 * 4) =
        *(const float4*)(EWS + (bb * NT + t0 + r) * NH + c4 * 4);
  }
  __syncthreads();

  // V0 = sum(v) via one float2 read + wave shuffles (all lanes get it)
  float V0;
  {
    float2 vv = *(const float2*)(s_v + (tid & 63) * 2);
    V0 = vv.x + vv.y;
    #pragma unroll
    for (int msk = 1; msk <= 32; msk <<= 1)
      V0 += __shfl_xor(V0, msk, 64);
  }

  // ---- Phase B: scores. Thread sp owns 2 contiguous s, ALL 128 h, 4 t.
  // Wave-level skip of fully-masked 128-s spans.
  const int sp = tid;
  const int sbase = sp * 2;
  float2 acc2[4];
  #pragma unroll
  for (int i = 0; i < 4; ++i) { acc2[i].x = 0.f; acc2[i].y = 0.f; }
  const int wave_s0 = (tid & ~63) * 2;    // wave-uniform start of 128-s span
  if (wave_s0 < len) {
    const float* fb = EWHT + bb * NH * NS + sbase;
    for (int ho = 0; ho < 16; ++ho) {     // 8 h-rows per iter
      const float* fh = fb + ho * 8 * NS;
      float2 F0 = *(const float2*)(fh + 0 * NS);   // 512B/wave per row (L2)
      float2 F1 = *(const float2*)(fh + 1 * NS);
      float2 F2 = *(const float2*)(fh + 2 * NS);
      float2 F3 = *(const float2*)(fh + 3 * NS);
      float2 F4 = *(const float2*)(fh + 4 * NS);
      float2 F5 = *(const float2*)(fh + 5 * NS);
      float2 F6 = *(const float2*)(fh + 6 * NS);
      float2 F7 = *(const float2*)(fh + 7 * NS);
      float4 va = *(const float4*)(s_v + ho * 8);      // block-uniform
      float4 vb = *(const float4*)(s_v + ho * 8 + 4);
      #pragma unroll
      for (int tt = 0; tt < 4; ++tt) {
        float4 e0 = *(const float4*)(s_et + tt * 132 + ho * 8);  // bcast
        float4 e1 = *(const float4*)(s_et + tt * 132 + ho * 8 + 4);
        acc2[tt] = quad_acc2(e0, va, F0, F1, F2, F3, acc2[tt]);
        acc2[tt] = quad_acc2(e1, vb, F4, F5, F6, F7, acc2[tt]);
      }
    }
  }
  #pragma unroll
  for (int tt = 0; tt < 4; ++tt) {       // no cross-thread reduce needed
    float2 r;  // faithful quirk: masked scores ZEROED, still in softmax
    r.x = (sbase + 0 < len) ? fmaf(-2.f, acc2[tt].x, V0) : 0.f;
    r.y = (sbase + 1 < len) ? fmaf(-2.f, acc2[tt].y, V0) : 0.f;
    *(float2*)(s_sc + tt * 516 + sbase) = r;  // contiguous 512B/wave
  }
  __syncthreads();

  // ---- Phase C: softmax per t-row; attn transposed into s_aT ----
  const int t = tid & 3;
  const int c = tid >> 2;       // 0..63, 8 strided s values each
  const int wv = tid >> 6;
  float pv[8];
  float mx = -3.4e38f;
  #pragma unroll
  for (int k = 0; k < 8; ++k) {
    pv[k] = s_sc[t * 516 + c + 64 * k];
    mx = fmaxf(mx, pv[k]);
  }
  #pragma unroll
  for (int msk = 4; msk <= 32; msk <<= 1)
    mx = fmaxf(mx, __shfl_xor(mx, msk, 64));
  if ((tid & 63) < 4) s_red[wv * 4 + t] = mx;
  __syncthreads();
  #pragma unroll
  for (int j = 0; j < 4; ++j) mx = fmaxf(mx, s_red[j * 4 + t]);
  __syncthreads();              // all reads done before red is rewritten
  float sum = 0.f;
  #pragma unroll
  for (int k = 0; k < 8; ++k) {
    pv[k] = fast_exp2((pv[k] - mx) * 1.4426950408889634f);
    sum += pv[k];
  }
  #pragma unroll
  for (int msk = 4; msk <= 32; msk <<= 1)
    sum += __shfl_xor(sum, msk, 64);
  if ((tid & 63) < 4) s_red[wv * 4 + t] = sum;
  __syncthreads();
  sum = 0.f;
  #pragma unroll
  for (int j = 0; j < 4; ++j) sum += s_red[j * 4 + t];
  const float rd = fast_rcp(sum);
  #pragma unroll
  for (int k = 0; k < 8; ++k)   // word 4(c+64k)+t: consecutive per wave
    s_aT[(c + 64 * k) * 4 + t] = pv[k] * rd;
  __syncthreads();

  // ---- Phase D': pre_out[t][c] = sum_s attn[t][s] * ENCW[s][c] ----
  // 8 s-groups x 64 s; one float4 attn read covers all 4 t-rows.
  const int hg = tid & 31, sg = tid >> 5;
  float4 a8[4] = {{0,0,0,0},{0,0,0,0},{0,0,0,0},{0,0,0,0}};
  const float* eb = ENCW + bb * NS * NH + hg * 4;
  for (int k = 0; k < 64; ++k) {
    int s = sg * 64 + k;
    float4 e = *(const float4*)(eb + s * NH);       // coalesced global
    float4 w = *(const float4*)(s_aT + s * 4);      // 2 addrs/wave: free
    a8[0].x += w.x*e.x; a8[0].y += w.x*e.y; a8[0].z += w.x*e.z; a8[0].w += w.x*e.w;
    a8[1].x += w.y*e.x; a8[1].y += w.y*e.y; a8[1].z += w.y*e.z; a8[1].w += w.y*e.w;
    a8[2].x += w.z*e.x; a8[2].y += w.z*e.y; a8[2].z += w.z*e.z; a8[2].w += w.z*e.w;
    a8[3].x += w.w*e.x; a8[3].y += w.w*e.y; a8[3].z += w.w*e.z; a8[3].w += w.w*e.w;
  }
  #pragma unroll
  for (int i = 0; i < 4; ++i) {     // sg pairs within wave (lane^32)
    a8[i].x += __shfl_xor(a8[i].x, 32, 64);
    a8[i].y += __shfl_xor(a8[i].y, 32, 64);
    a8[i].z += __shfl_xor(a8[i].z, 32, 64);
    a8[i].w += __shfl_xor(a8[i].w, 32, 64);
  }
  float* lred = s_sc;               // overlay (dead): needs 2048 <= 2064
  if ((tid & 63) < 32) {
    #pragma unroll
    for (int i = 0; i < 4; ++i)
      *(float4*)(lred + wv * 512 + i * 128 + hg * 4) = a8[i];
  }
  __syncthreads();
  {                                 // final reduce + QW2 (has bias) + tanh
    int tt = tid >> 6, h2 = tid & 63;
    float2 o = {0.f, 0.f};
    #pragma unroll
    for (int j = 0; j < 4; ++j) {
      float2 p = *(const float2*)(lred + j * 512 + tt * 128 + h2 * 2);
      o.x += p.x; o.y += p.y;
    }
    const int row = bb * NT + t0 + tt;
    float2 q2 = *(const float2*)(QW2 + row * NH + h2 * 2);  // coalesced
    float2 r;
    r.x = fast_tanh(o.x + q2.x);
    r.y = fast_tanh(o.y + q2.y);
    *(float2*)(out + row * NH + h2 * 2) = r;
  }
}

extern "C" void kernel_launch(void* const* d_in, const int* in_sizes, int n_in,
                              void* d_out, int out_size, void* d_ws, size_t ws_size,
                              hipStream_t stream) {
  const float* query = (const float*)d_in[0];
  const float* enc   = (const float*)d_in[1];
  const int*   slen  = (const int*)d_in[2];
  const float* W_h   = (const float*)d_in[3];
  const float* W_s   = (const float*)d_in[4];
  const float* v     = (const float*)d_in[5];
  const float* Woutw = (const float*)d_in[6];
  const float* Woutb = (const float*)d_in[7];
  float* out = (float*)d_out;

  float* ws = (float*)d_ws;
  float* EWS  = ws;                  // B*T*H (2 MB)
  float* EWHT = ws + 524288;         // B*H*S transposed (2 MB)
  float* ENCW = ws + 1048576;        // B*S*H = enc @ W1^T (2 MB)
  float* QW2  = ws + 1572864;        // B*T*H = q @ W2^T + bias (2 MB)

  bah_proj_kernel<<<1024, 256, 0, stream>>>(query, enc, W_s, W_h, Woutw,
                                            Woutb, EWS, EWHT, ENCW, QW2);
  bah_mega_kernel<<<1024, 256, 0, stream>>>(EWS, EWHT, v, ENCW, QW2, slen, out);
}